// Round 3
// baseline (289.662 us; speedup 1.0000x reference)
//
#include <hip/hip_runtime.h>
#include <hip/hip_bf16.h>

typedef unsigned int uint;
typedef unsigned short ushort;
typedef __bf16 bf16x8 __attribute__((ext_vector_type(8)));
typedef float f32x4 __attribute__((ext_vector_type(4)));
typedef unsigned short u16x2 __attribute__((ext_vector_type(2)));

#define T_TOK 1024
#define HDIM 2880
#define IDIM 2880
#define NEXP 8
#define GU 5760
#define QK1 1440
#define SG1 90
#define QK2 1440
#define SG2 90
#define MAXR 2048
#define NK 45
#define BM 320          // rows per m-tile: cnt ~256±15 -> 1 tile, 20% pad waste

#define ZROW_OFF 65536u
#define HB_OFF 131072u
#define GATED_OFF_PRE 6029312u              // HB_OFF + 1024*2880*2
#define WS_NEED (GATED_OFF_PRE + (size_t)MAXR * IDIM * 2)

// T2 swizzle: 128B LDS rows, 16B chunk index XORed with row&7.
// Writes: 8 consecutive lanes cover one row's 8 chunks -> conflict-free.
// Reads: 16 lanes read rows r0..r0+15 at fixed chunk -> swz spreads banks (m201).
static __device__ __forceinline__ int ls(int row, int c) {
  return (row << 6) + (((c ^ row) & 7) << 3);
}

static __device__ __forceinline__ uint pkadd16(uint a, uint b) {
  u16x2 x = __builtin_bit_cast(u16x2, a);
  u16x2 y = __builtin_bit_cast(u16x2, b);
  u16x2 r = x + y;
  return __builtin_bit_cast(uint, r);
}

// Decode 4 fp4-pair bytes (one byte per int32, packed into P) into 4 dwords of
// 2×bf16 (low nibble = even k first), E8M0 scale fused as exponent add (exact).
static __device__ __forceinline__ void decode8(uint P, uint sAdd2, uint out[4]) {
  uint L  = P & 0x0F0F0F0Fu;
  uint Hh = (P >> 4) & 0x0F0F0F0Fu;
  uint Lm = L & 0x07070707u,  Hm = Hh & 0x07070707u;
  uint Lsg = (L & 0x08080808u) << 4, Hsg = (Hh & 0x08080808u) << 4;
  uint hiL = __builtin_amdgcn_perm(0x40404040u, 0x3F3F3F00u, Lm) | Lsg;
  uint hiH = __builtin_amdgcn_perm(0x40404040u, 0x3F3F3F00u, Hm) | Hsg;
  uint loL = __builtin_amdgcn_perm(0xC0804000u, 0xC0800000u, Lm);
  uint loH = __builtin_amdgcn_perm(0xC0804000u, 0xC0800000u, Hm);
  uint mL  = __builtin_amdgcn_perm(0xFFFFFFFFu, 0xFFFFFF00u, Lm);
  uint mH  = __builtin_amdgcn_perm(0xFFFFFFFFu, 0xFFFFFF00u, Hm);
  uint pL01 = __builtin_amdgcn_perm(hiL, loL, 0x05010400u);
  uint pL23 = __builtin_amdgcn_perm(hiL, loL, 0x07030602u);
  uint pH01 = __builtin_amdgcn_perm(hiH, loH, 0x05010400u);
  uint pH23 = __builtin_amdgcn_perm(hiH, loH, 0x07030602u);
  uint aL01 = pkadd16(pL01, sAdd2 & __builtin_amdgcn_perm(mL, mL, 0x01010000u));
  uint aL23 = pkadd16(pL23, sAdd2 & __builtin_amdgcn_perm(mL, mL, 0x03030202u));
  uint aH01 = pkadd16(pH01, sAdd2 & __builtin_amdgcn_perm(mH, mH, 0x01010000u));
  uint aH23 = pkadd16(pH23, sAdd2 & __builtin_amdgcn_perm(mH, mH, 0x03030202u));
  out[0] = __builtin_amdgcn_perm(aH01, aL01, 0x05040100u);
  out[1] = __builtin_amdgcn_perm(aH01, aL01, 0x07060302u);
  out[2] = __builtin_amdgcn_perm(aH23, aL23, 0x05040100u);
  out[3] = __builtin_amdgcn_perm(aH23, aL23, 0x07060302u);
}

static __device__ __forceinline__ uint packbf2(float a, float b) {
  ushort ua = __builtin_bit_cast(ushort, __float2bfloat16(a));
  ushort ub = __builtin_bit_cast(ushort, __float2bfloat16(b));
  return (uint)ua | ((uint)ub << 16);
}

// ---------- kernel 0: routed-row lists ----------

__global__ void build_lists_kernel(const int* __restrict__ ridx,
                                   int* __restrict__ counts,
                                   int* __restrict__ lists) {
  int r = blockIdx.x * 256 + threadIdx.x;
  if (r >= MAXR) return;
  int e = ridx[r];
  int pos = atomicAdd(&counts[e], 1);
  lists[e * MAXR + pos] = r;
}

// ---------- kernel 0b: hidden f32 -> bf16 ----------

__global__ void cvt_kernel(const float* __restrict__ in, ushort* __restrict__ out) {
  int i = (blockIdx.x * 256 + threadIdx.x) * 8;
  float4 a = *(const float4*)(in + i);
  float4 b = *(const float4*)(in + i + 4);
  uint4 o;
  o.x = packbf2(a.x, a.y); o.y = packbf2(a.z, a.w);
  o.z = packbf2(b.x, b.y); o.w = packbf2(b.z, b.w);
  *(uint4*)(out + i) = o;
}

// ---------- kernel 1: gate_up GEMM + activation -> gated ----------
// 256 thr (4 waves), BM=320 x BN=64 gu-rows, flat grid: e = bid&7 (XCD-affine),
// xt = bid>>3 (90 tiles). A staged via global_load_lds with pre-swizzled global
// addresses; B decoded in-reg.

template <bool PRE>
__global__ __launch_bounds__(256, 3)
void gemm1_kernel(const char* __restrict__ wsb,
                  const float* __restrict__ hiddenF,
                  const int* __restrict__ guq,
                  const int* __restrict__ gus,
                  const float* __restrict__ gub,
                  const int* __restrict__ counts,
                  const int* __restrict__ lists,
                  ushort* __restrict__ gated) {
  const int e  = blockIdx.x & 7;
  const int xt = blockIdx.x >> 3;
  const int cnt = counts[e];
  const int mt = blockIdx.y;
  if (mt * BM >= cnt) return;
  const int gu0 = xt * 64;
  const int tid = threadIdx.x;

  __shared__ ushort lA[BM * 64];
  __shared__ ushort lB[64 * 64];
  __shared__ int rowid[BM];

  for (int i = tid; i < BM; i += 256) {
    int rl = mt * BM + i;
    rowid[i] = (rl < cnt) ? lists[e * MAXR + rl] : -1;
  }
  __syncthreads();

  const int ln = tid & 63, wv = tid >> 6;
  const int ln15 = ln & 15, kq = ln >> 4;

  // ---- A staging setup ----
  uint aoff[10];
  uint avalid = 0;
  if (PRE) {
    // DMA call j stages LDS slots [wv*640+j*64, +64): lane ln -> slot base+ln.
    // Global source pre-swizzled so linear LDS dest realizes the T2 layout.
    #pragma unroll
    for (int j = 0; j < 10; ++j) {
      int slot = wv * 640 + j * 64 + ln;
      int row  = slot >> 3;
      int corig = (slot ^ row) & 7;
      int r = rowid[row];
      aoff[j] = (r >= 0) ? (HB_OFF + (uint)(r >> 1) * (HDIM * 2) + corig * 16)
                         : (ZROW_OFF + corig * 16);
    }
  } else {
    #pragma unroll
    for (int j = 0; j < 10; ++j) {
      int row = (tid >> 3) + 32 * j;
      int r = rowid[row];
      if (r >= 0) avalid |= 1u << j;
      uint tok = (r >= 0) ? (uint)(r >> 1) : 0u;
      aoff[j] = tok * (HDIM * 4) + (uint)(tid & 7) * 32;
    }
  }

  // ---- B staging setup: row = tid>>2 (0..63), 32B chunk c2 = tid&3 ----
  const int brow = tid >> 2, c2 = tid & 3;
  const uint grow = (uint)(e * GU + gu0 + brow);
  const uint boff0 = grow * (QK1 * 4) + (uint)c2 * 32;
  const uint soff0 = grow * (SG1 * 4) + (uint)(c2 >> 1) * 4;

  f32x4 acc[5][4];
  #pragma unroll
  for (int m = 0; m < 5; ++m)
    #pragma unroll
    for (int n = 0; n < 4; ++n) acc[m][n] = (f32x4)0.f;

  const char* gq = (const char*)guq;
  const char* gs = (const char*)gus;

  for (int ks = 0; ks < NK; ++ks) {
    // B loads (manual decode path)
    int4 bv0 = *(const int4*)(gq + boff0 + (uint)ks * 128);
    int4 bv1 = *(const int4*)(gq + boff0 + (uint)ks * 128 + 16);
    int  sv  = *(const int*)(gs + soff0 + (uint)ks * 8);
    // A staging
    if (PRE) {
      #pragma unroll
      for (int j = 0; j < 10; ++j) {
        __builtin_amdgcn_global_load_lds(
            (const __attribute__((address_space(1))) void*)(wsb + aoff[j] + (uint)ks * 128),
            (__attribute__((address_space(3))) void*)((char*)lA + (wv * 640 + j * 64) * 16),
            16, 0, 0);
      }
    } else {
      #pragma unroll
      for (int j = 0; j < 10; ++j) {
        int row = (tid >> 3) + 32 * j;
        uint4 o;
        if (avalid & (1u << j)) {
          const float4* f = (const float4*)((const char*)hiddenF + aoff[j] + (size_t)ks * 256);
          float4 f0 = f[0], f1 = f[1];
          o.x = packbf2(f0.x, f0.y); o.y = packbf2(f0.z, f0.w);
          o.z = packbf2(f1.x, f1.y); o.w = packbf2(f1.z, f1.w);
        } else { o.x = o.y = o.z = o.w = 0u; }
        *(uint4*)&lA[ls(row, tid & 7)] = o;
      }
    }
    // B decode + LDS write (chunks 2c2, 2c2+1)
    {
      uint P0 = (uint)bv0.x | ((uint)bv0.y << 8) | ((uint)bv0.z << 16) | ((uint)bv0.w << 24);
      uint P1 = (uint)bv1.x | ((uint)bv1.y << 8) | ((uint)bv1.z << 16) | ((uint)bv1.w << 24);
      uint sOff = ((uint)(sv - 127) << 7) & 0xFFFFu;
      uint sAdd2 = sOff | (sOff << 16);
      uint o0[4], o1[4];
      decode8(P0, sAdd2, o0);
      decode8(P1, sAdd2, o1);
      uint4 w0; w0.x = o0[0]; w0.y = o0[1]; w0.z = o0[2]; w0.w = o0[3];
      uint4 w1; w1.x = o1[0]; w1.y = o1[1]; w1.z = o1[2]; w1.w = o1[3];
      *(uint4*)&lB[ls(brow, 2 * c2)]     = w0;
      *(uint4*)&lB[ls(brow, 2 * c2 + 1)] = w1;
    }
    __syncthreads();
    __builtin_amdgcn_s_setprio(1);
    #pragma unroll
    for (int kf = 0; kf < 2; ++kf) {
      const int cc = 4 * kf + kq;
      bf16x8 bfr[4];
      #pragma unroll
      for (int n = 0; n < 4; ++n)
        bfr[n] = *(const bf16x8*)&lB[ls(n * 16 + ln15, cc)];
      #pragma unroll
      for (int m = 0; m < 5; ++m) {
        bf16x8 af = *(const bf16x8*)&lA[ls(wv * 80 + m * 16 + ln15, cc)];
        #pragma unroll
        for (int n = 0; n < 4; ++n)
          acc[m][n] = __builtin_amdgcn_mfma_f32_16x16x32_bf16(af, bfr[n], acc[m][n], 0, 0, 0);
      }
    }
    __builtin_amdgcn_s_setprio(0);
    __syncthreads();
  }

  // ---- epilogue: bias, pair g/u via shfl_xor(1), glu, write bf16 ----
  float bias[4];
  #pragma unroll
  for (int n = 0; n < 4; ++n)
    bias[n] = gub[(size_t)e * GU + gu0 + n * 16 + ln15];
  #pragma unroll
  for (int m = 0; m < 5; ++m) {
    #pragma unroll
    for (int rg = 0; rg < 4; ++rg) {
      int row = wv * 80 + m * 16 + kq * 4 + rg;
      int r = rowid[row];
      #pragma unroll
      for (int n = 0; n < 4; ++n) {
        float x = acc[m][n][rg] + bias[n];
        float y = __shfl_xor(x, 1);
        if (r >= 0 && !(ln & 1)) {
          float g = fminf(x, 7.f);
          float u = fminf(fmaxf(y, -7.f), 7.f);
          float glu = g / (1.f + __expf(-1.702f * g));
          float val = (u + 1.f) * glu;
          int gucol = gu0 + n * 16 + ln15;
          gated[(size_t)r * IDIM + (gucol >> 1)] =
              __builtin_bit_cast(ushort, __float2bfloat16(val));
        }
      }
    }
  }
}

// ---------- kernel 2: down GEMM + routed scatter-add ----------
// 256 thr, BM=320 x BN=32 h-cols, flat grid e = bid&7, ht = bid>>3 (90 tiles).

__global__ __launch_bounds__(256, 3)
void gemm2_kernel(const char* __restrict__ wsb, uint gatedOff,
                  const int* __restrict__ dq,
                  const int* __restrict__ dsc,
                  const float* __restrict__ dpb,
                  const float* __restrict__ routing,
                  const int* __restrict__ counts,
                  const int* __restrict__ lists,
                  float* __restrict__ outp) {
  const int e  = blockIdx.x & 7;
  const int ht = blockIdx.x >> 3;
  const int cnt = counts[e];
  const int mt = blockIdx.y;
  if (mt * BM >= cnt) return;
  const int h0 = ht * 32;
  const int tid = threadIdx.x;

  __shared__ ushort lA[BM * 64];
  __shared__ ushort lB[32 * 64];
  __shared__ int rowid[BM];

  for (int i = tid; i < BM; i += 256) {
    int rl = mt * BM + i;
    rowid[i] = (rl < cnt) ? lists[e * MAXR + rl] : -1;
  }
  __syncthreads();

  const int ln = tid & 63, wv = tid >> 6;
  const int ln15 = ln & 15, kq = ln >> 4;

  uint aoff[10];
  #pragma unroll
  for (int j = 0; j < 10; ++j) {
    int slot = wv * 640 + j * 64 + ln;
    int row  = slot >> 3;
    int corig = (slot ^ row) & 7;
    int r = rowid[row];
    aoff[j] = (r >= 0) ? (gatedOff + (uint)r * (IDIM * 2) + corig * 16)
                       : (ZROW_OFF + corig * 16);
  }
  const int brow = tid >> 2, c2 = tid & 3;   // only brow<32 active for B
  const bool bact = (brow < 32);
  const uint hrow = (uint)(e * HDIM + h0 + (brow & 31));
  const uint boff0 = hrow * (QK2 * 4) + (uint)c2 * 32;
  const uint soff0 = hrow * (SG2 * 4) + (uint)(c2 >> 1) * 4;

  f32x4 acc[5][2];
  #pragma unroll
  for (int m = 0; m < 5; ++m) { acc[m][0] = (f32x4)0.f; acc[m][1] = (f32x4)0.f; }

  const char* gq = (const char*)dq;
  const char* gs = (const char*)dsc;

  for (int ks = 0; ks < NK; ++ks) {
    int4 bv0, bv1; int sv = 0;
    if (bact) {
      bv0 = *(const int4*)(gq + boff0 + (uint)ks * 128);
      bv1 = *(const int4*)(gq + boff0 + (uint)ks * 128 + 16);
      sv  = *(const int*)(gs + soff0 + (uint)ks * 8);
    }
    #pragma unroll
    for (int j = 0; j < 10; ++j) {
      __builtin_amdgcn_global_load_lds(
          (const __attribute__((address_space(1))) void*)(wsb + aoff[j] + (uint)ks * 128),
          (__attribute__((address_space(3))) void*)((char*)lA + (wv * 640 + j * 64) * 16),
          16, 0, 0);
    }
    if (bact) {
      uint P0 = (uint)bv0.x | ((uint)bv0.y << 8) | ((uint)bv0.z << 16) | ((uint)bv0.w << 24);
      uint P1 = (uint)bv1.x | ((uint)bv1.y << 8) | ((uint)bv1.z << 16) | ((uint)bv1.w << 24);
      uint sOff = ((uint)(sv - 127) << 7) & 0xFFFFu;
      uint sAdd2 = sOff | (sOff << 16);
      uint o0[4], o1[4];
      decode8(P0, sAdd2, o0);
      decode8(P1, sAdd2, o1);
      uint4 w0; w0.x = o0[0]; w0.y = o0[1]; w0.z = o0[2]; w0.w = o0[3];
      uint4 w1; w1.x = o1[0]; w1.y = o1[1]; w1.z = o1[2]; w1.w = o1[3];
      *(uint4*)&lB[ls(brow & 31, 2 * c2)]     = w0;
      *(uint4*)&lB[ls(brow & 31, 2 * c2 + 1)] = w1;
    }
    __syncthreads();
    __builtin_amdgcn_s_setprio(1);
    #pragma unroll
    for (int kf = 0; kf < 2; ++kf) {
      const int cc = 4 * kf + kq;
      bf16x8 bfr[2];
      #pragma unroll
      for (int n = 0; n < 2; ++n)
        bfr[n] = *(const bf16x8*)&lB[ls(n * 16 + ln15, cc)];
      #pragma unroll
      for (int m = 0; m < 5; ++m) {
        bf16x8 af = *(const bf16x8*)&lA[ls(wv * 80 + m * 16 + ln15, cc)];
        #pragma unroll
        for (int n = 0; n < 2; ++n)
          acc[m][n] = __builtin_amdgcn_mfma_f32_16x16x32_bf16(af, bfr[n], acc[m][n], 0, 0, 0);
      }
    }
    __builtin_amdgcn_s_setprio(0);
    __syncthreads();
  }

  float bias[2];
  #pragma unroll
  for (int n = 0; n < 2; ++n)
    bias[n] = dpb[(size_t)e * HDIM + h0 + n * 16 + ln15];
  #pragma unroll
  for (int m = 0; m < 5; ++m) {
    #pragma unroll
    for (int rg = 0; rg < 4; ++rg) {
      int row = wv * 80 + m * 16 + kq * 4 + rg;
      int r = rowid[row];
      if (r < 0) continue;
      float wgt = routing[r];
      #pragma unroll
      for (int n = 0; n < 2; ++n) {
        int hcol = h0 + n * 16 + ln15;
        atomicAdd(outp + (size_t)(r >> 1) * HDIM + hcol,
                  wgt * (acc[m][n][rg] + bias[n]));
      }
    }
  }
}

// ---------- launch ----------

extern "C" void kernel_launch(void* const* d_in, const int* in_sizes, int n_in,
                              void* d_out, int out_size, void* d_ws, size_t ws_size,
                              hipStream_t stream) {
  const float* hidden  = (const float*)d_in[0];
  const float* routing = (const float*)d_in[1];
  const float* gub     = (const float*)d_in[2];
  const float* dpb     = (const float*)d_in[3];
  const int*   ridx    = (const int*)d_in[4];
  const int*   guq     = (const int*)d_in[5];
  const int*   gus     = (const int*)d_in[6];
  const int*   dq      = (const int*)d_in[7];
  const int*   dsc     = (const int*)d_in[8];
  float* outp = (float*)d_out;

  char* ws = (char*)d_ws;
  int* counts = (int*)ws;
  int* lists  = (int*)(ws + 256);
  const bool pre = (ws_size >= WS_NEED);
  const uint gatedOff = pre ? GATED_OFF_PRE : HB_OFF;
  ushort* hb    = (ushort*)(ws + HB_OFF);
  ushort* gated = (ushort*)(ws + gatedOff);

  hipMemsetAsync(counts, 0, 256, stream);
  hipMemsetAsync(ws + ZROW_OFF, 0, 5760, stream);
  hipMemsetAsync(d_out, 0, (size_t)out_size * sizeof(float), stream);

  build_lists_kernel<<<MAXR / 256, 256, 0, stream>>>(ridx, counts, lists);
  if (pre)
    cvt_kernel<<<(T_TOK * HDIM / 8) / 256, 256, 0, stream>>>(hidden, hb);

  dim3 grid1((GU / 64) * NEXP, (MAXR + BM - 1) / BM);
  if (pre)
    gemm1_kernel<true><<<grid1, 256, 0, stream>>>(ws, hidden, guq, gus, gub,
                                                  counts, lists, gated);
  else
    gemm1_kernel<false><<<grid1, 256, 0, stream>>>(ws, hidden, guq, gus, gub,
                                                   counts, lists, gated);

  dim3 grid2((HDIM / 32) * NEXP, (MAXR + BM - 1) / BM);
  gemm2_kernel<<<grid2, 256, 0, stream>>>(ws, gatedOff, dq, dsc, dpb, routing,
                                          counts, lists, outp);
}